// Round 14
// baseline (124.090 us; speedup 1.0000x reference)
//
#include <hip/hip_runtime.h>
#include <hip/hip_bf16.h>
#include <stdint.h>

#define HH 8
#define DD 128
#define MAXSEQ 2048
#define QBLK 64

typedef float f32x16 __attribute__((ext_vector_type(16)));
typedef short s16x8 __attribute__((ext_vector_type(8)));

__device__ __forceinline__ unsigned short f2bf(float x) {
  union { float f; uint32_t u; } v; v.f = x;
  uint32_t u = v.u;
  return (unsigned short)((u + 0x7FFFu + ((u >> 16) & 1u)) >> 16);
}

__device__ __forceinline__ void gload_lds16(const unsigned short* g, unsigned short* l) {
  __builtin_amdgcn_global_load_lds((const __attribute__((address_space(1))) void*)g,
                                   (__attribute__((address_space(3))) void*)l, 16, 0, 0);
}

// ---- prepass 0: zero rows not covered by any sequence ----
__global__ void zero_rows(const int* __restrict__ cuq, float* __restrict__ out, int T, int B) {
  const int t = blockIdx.x * blockDim.x + threadIdx.x;
  if (t >= T) return;
  bool covered = false;
  for (int b = 0; b < B; ++b) {
    const int s = cuq[b];
    const int len = min(cuq[b + 1] - s, MAXSEQ);
    if (t >= s && t < s + len) covered = true;
  }
  if (!covered) {
    float4* p = (float4*)(out + (size_t)t * HH * DD);
#pragma unroll 4
    for (int i = 0; i < HH * DD / 4; ++i) p[i] = float4{0.f, 0.f, 0.f, 0.f};
  }
}

// ---- fused prepass: K,V [T,H,D] f32 -> fragment-native bf16 unit layouts ----
// (identical to R10; verified) K unit: K[tb*32+(lane&31)][c*16+(lane>>5)*8+j];
// V unit with pi-permutation so P pack is lane-local.
__global__ void kvconv(const float* __restrict__ k, const float* __restrict__ v,
                       unsigned short* __restrict__ kb2, unsigned short* __restrict__ vb2, int T) {
  const int TBc = T >> 5;
  const int total = TBc * HH * 512;
  int u = blockIdx.x * blockDim.x + threadIdx.x;
  if (u < total) {
    const int lp = u & 63;
    const int key = lp & 31, hi = lp >> 5;
    int r = u >> 6;
    const int c = r & 7; r >>= 3;
    const int tb = r % TBc;
    const int h = r / TBc;
    const int t = tb * 32 + key;
    const int d = c * 16 + hi * 8;
    const float* src = k + ((size_t)t * HH + h) * DD + d;
    float4 a = *(const float4*)src;
    float4 cc = *(const float4*)(src + 4);
    union { unsigned short us[8]; uint4 q; } w;
    w.us[0] = f2bf(a.x); w.us[1] = f2bf(a.y); w.us[2] = f2bf(a.z); w.us[3] = f2bf(a.w);
    w.us[4] = f2bf(cc.x); w.us[5] = f2bf(cc.y); w.us[6] = f2bf(cc.z); w.us[7] = f2bf(cc.w);
    *(uint4*)(kb2 + (size_t)u * 8) = w.q;
  } else if ((u -= total) < total) {
    const int lo = u & 31;
    const int hi = (u >> 5) & 1;
    const int i = (u >> 6) & 7;
    const int dt = i & 3, ks2 = i >> 2;
    int r = u >> 9;
    const int tb = r % TBc;
    const int h = r / TBc;
    const int d = dt * 32 + lo;
    union { unsigned short us[8]; uint4 q; } w;
#pragma unroll
    for (int j = 0; j < 8; ++j) {
      const int phys = 16 * ks2 + ((j < 4) ? (4 * hi + j) : (8 + 4 * hi + (j - 4)));
      const int t = tb * 32 + phys;
      w.us[j] = f2bf(v[((size_t)t * HH + h) * DD + d]);
    }
    *(uint4*)(vb2 + (size_t)u * 8) = w.q;
  }
}

// ---- main: split-KV x2. Block = 256 threads = 4 waves = (2 q-strips) x (2 kv-halves).
// Each wave: 32 q rows x its 1024-key half, 32-key tiles. K via shared LDS dbuf
// (per-half slots, fragment-native linear = conflict-free); V direct global ->
// transient regs; fixed-shift softmax -> merge of halves is a PURE SUM (no max).
// 1024 blocks -> 4/CU -> up to 4 waves/SIMD (vs the structural 2 of 32q/wave).
__global__ __launch_bounds__(256, 3)
void attn_main(const float* __restrict__ q,
               const unsigned short* __restrict__ kb2,
               const unsigned short* __restrict__ vb2,
               const int* __restrict__ cuq,
               const int* __restrict__ cuk,
               float* __restrict__ out,
               int T, int BH) {
  extern __shared__ __align__(16) unsigned short smem[];
  // K slot (wk, buf): smem + (wk*2+buf)*4096 shorts (8KB each; 32KB total)
  // merge phase reuses smem as float buffer (32KB Oa + 256B l)

  const int TBc = T >> 5;
  const int bid = blockIdx.x;
  const int bh = bid % BH;
  const int qt = bid / BH;
  const int b = bh / HH, h = bh % HH;
  const int qs = cuq[b], qe = cuq[b + 1];
  const int ks = cuk[b], ke = cuk[b + 1];
  const int nq = min(qe - qs, MAXSEQ);
  const int nk = min(ke - ks, MAXSEQ);
  if (qt * QBLK >= nq || nk <= 0) return;

  const int tid = threadIdx.x;
  const int wave = tid >> 6;
  const int lane = tid & 63;
  const int lo = lane & 31;
  const int hi = lane >> 5;
  const int wq = wave & 1;   // q-strip
  const int wk = wave >> 1;  // kv-half

  const int kb32 = ks >> 5;  // sequence starts 32-aligned in this problem
  const unsigned short* kb2h = kb2 + (size_t)h * TBc * 4096;
  const unsigned short* vb2h = vb2 + (size_t)h * TBc * 4096;

  // ---- Q fragments; fold 1/sqrt(D)*log2(e) ----
  const float SC = (1.0f / 11.313708498984761f) * 1.4426950408889634f;
  const int qrow = qt * QBLK + wq * 32 + lo;
  const int qg = qs + min(qrow, nq - 1);
  const float* qp = q + ((size_t)qg * HH + h) * DD;
  s16x8 qf[8];
#pragma unroll
  for (int c = 0; c < 8; ++c) {
    const float* p0 = qp + c * 16 + hi * 8;
    float4 a = *(const float4*)(p0);
    float4 cc = *(const float4*)(p0 + 4);
    union { unsigned short us[8]; s16x8 v; } u;
    u.us[0] = f2bf(a.x * SC); u.us[1] = f2bf(a.y * SC);
    u.us[2] = f2bf(a.z * SC); u.us[3] = f2bf(a.w * SC);
    u.us[4] = f2bf(cc.x * SC); u.us[5] = f2bf(cc.y * SC);
    u.us[6] = f2bf(cc.z * SC); u.us[7] = f2bf(cc.w * SC);
    qf[c] = u.v;
  }

  f32x16 Oa[4];
#pragma unroll
  for (int i = 0; i < 4; ++i)
#pragma unroll
    for (int r = 0; r < 16; ++r) Oa[i][r] = 0.0f;

  float l_run = 0.0f;

  // this wave's kv-half: tiles of 32 keys
  const int len_wk = min(nk - wk * 1024, 1024);               // may be <= 0
  const int myT = len_wk > 0 ? (len_wk + 31) / 32 : 0;
  const int nkt = (min(nk, 1024) + 31) / 32;                  // uniform loop count (half0 >= half1)
  const int tb0 = kb32 + wk * 32;                             // this half's first tile-block

  // ---- K staging: both halves' tiles, linear fragment-native copy (16KB/iter) ----
  auto stageK = [&](int buf, int kt) {
#pragma unroll
    for (int r = 0; r < 4; ++r) {
      const int half = r >> 1;
      const int tb = min(kb32 + half * 32 + kt, TBc - 1);
      const int ul = (r & 1) * 256 + tid;  // unit within the 8KB tile
      gload_lds16(kb2h + (size_t)tb * 4096 + (size_t)ul * 8,
                  smem + (size_t)(half * 2 + buf) * 4096 + (size_t)((r & 1) * 256 + (tid & ~63)) * 8);
    }
  };

  stageK(0, 0);
  __syncthreads();

  int buf = 0;
  for (int kt = 0; kt < nkt; ++kt) {
    if (kt + 1 < nkt) stageK(buf ^ 1, kt + 1);

    if (kt < myT) {
      const unsigned short* Kslot = smem + (size_t)(wk * 2 + buf) * 4096;
      const int tb = min(tb0 + kt, TBc - 1);

      // ---- QK: one 32-key tile from LDS (conflict-free contiguous reads) ----
      f32x16 st;
#pragma unroll
      for (int r = 0; r < 16; ++r) st[r] = 0.0f;
      {
        s16x8 kf[8];
#pragma unroll
        for (int c = 0; c < 8; ++c) kf[c] = *(const s16x8*)(Kslot + c * 512 + lane * 8);
        __builtin_amdgcn_s_setprio(1);
#pragma unroll
        for (int c = 0; c < 8; ++c)
          st = __builtin_amdgcn_mfma_f32_32x32x16_bf16(kf[c], qf[c], st, 0, 0, 0);
        __builtin_amdgcn_s_setprio(0);
      }

      // ---- V tile-block, first half (ks2=0): issue now, latency under softmax ----
      s16x8 vfA[4];
#pragma unroll
      for (int i = 0; i < 4; ++i)
        vfA[i] = *(const s16x8*)(vb2h + (size_t)tb * 4096 + i * 512 + lane * 8);

      // ---- tail mask (last partial tile of this half) ----
      const int lim = len_wk - kt * 32;
      if (lim < 32) {
#pragma unroll
        for (int r = 0; r < 16; ++r) {
          const int a = (r & 3) + 8 * (r >> 2) + 4 * hi;
          if (a >= lim) st[r] = -__builtin_inff();
        }
      }

      // ---- fixed-shift softmax (no shift; O/l cancels the common factor) ----
      float p[16];
#pragma unroll
      for (int r = 0; r < 16; ++r) p[r] = __builtin_amdgcn_exp2f(st[r]);
      float ps = 0.f;
#pragma unroll
      for (int r = 0; r < 16; r += 4) ps += (p[r] + p[r + 1]) + (p[r + 2] + p[r + 3]);
      l_run += ps;

      // ---- pack: lane-local cvt_pk (pi-layout; zero cross-lane exchange) ----
      uint32_t pw[8];
#pragma unroll
      for (int g = 0; g < 4; ++g) {
        uint32_t w0, w1;
        asm("v_cvt_pk_bf16_f32 %0, %1, %2" : "=v"(w0) : "v"(p[4 * g + 0]), "v"(p[4 * g + 1]));
        asm("v_cvt_pk_bf16_f32 %0, %1, %2" : "=v"(w1) : "v"(p[4 * g + 2]), "v"(p[4 * g + 3]));
        pw[2 * g] = w0;
        pw[2 * g + 1] = w1;
      }

      // ---- PV ks2=0 ----
      __builtin_amdgcn_s_setprio(1);
      {
        union { uint32_t u[4]; s16x8 v; } pa;
        pa.u[0] = pw[0]; pa.u[1] = pw[1]; pa.u[2] = pw[2]; pa.u[3] = pw[3];
#pragma unroll
        for (int dt = 0; dt < 4; ++dt)
          Oa[dt] = __builtin_amdgcn_mfma_f32_32x32x16_bf16(pa.v, vfA[dt], Oa[dt], 0, 0, 0);
      }
      __builtin_amdgcn_s_setprio(0);

      // ---- V second half (ks2=1) + PV ----
      s16x8 vfB[4];
#pragma unroll
      for (int i = 0; i < 4; ++i)
        vfB[i] = *(const s16x8*)(vb2h + (size_t)tb * 4096 + (4 + i) * 512 + lane * 8);
      __builtin_amdgcn_s_setprio(1);
      {
        union { uint32_t u[4]; s16x8 v; } pa;
        pa.u[0] = pw[4]; pa.u[1] = pw[5]; pa.u[2] = pw[6]; pa.u[3] = pw[7];
#pragma unroll
        for (int dt = 0; dt < 4; ++dt)
          Oa[dt] = __builtin_amdgcn_mfma_f32_32x32x16_bf16(pa.v, vfB[dt], Oa[dt], 0, 0, 0);
      }
      __builtin_amdgcn_s_setprio(0);
    }

    if (kt + 1 < nkt) {
      __syncthreads();  // drains K staging + joins waves
      buf ^= 1;
    }
  }

  // ---- merge the two kv-halves: fixed shift -> PURE SUM of (O, l) ----
  l_run += __shfl_xor(l_run, 32);  // lane lo now holds full l of q=lo for this half
  float* fbuf = (float*)smem;       // 8192 floats (32KB) for wk=1's Oa
  float* lbuf = fbuf + 8192;        // 64 floats for wk=1's l
  __syncthreads();                  // everyone done with K LDS
  if (wk == 1) {
#pragma unroll
    for (int r = 0; r < 16; ++r) {
      const int src = (r & 3) + 8 * (r >> 2) + 4 * hi;
      float* row = fbuf + (size_t)wq * 4096 + (size_t)src * 128;
      row[0 * 32 + lo] = Oa[0][r];
      row[1 * 32 + lo] = Oa[1][r];
      row[2 * 32 + lo] = Oa[2][r];
      row[3 * 32 + lo] = Oa[3][r];
    }
    if (hi == 0) lbuf[wq * 32 + lo] = l_run;
  }
  __syncthreads();
  if (wk == 0) {
    const float l_tot = l_run + lbuf[wq * 32 + lo];
    const float linv = 1.0f / l_tot;
#pragma unroll
    for (int r = 0; r < 16; ++r) {
      const int src = (r & 3) + 8 * (r >> 2) + 4 * hi;
      const float li = __shfl(linv, src);
      const int qirow = qt * QBLK + wq * 32 + src;
      if (qirow < nq) {
        const float* row = fbuf + (size_t)wq * 4096 + (size_t)src * 128;
        float* op = out + ((size_t)(qs + qirow) * HH + h) * DD;
        op[0 * 32 + lo] = (Oa[0][r] + row[0 * 32 + lo]) * li;
        op[1 * 32 + lo] = (Oa[1][r] + row[1 * 32 + lo]) * li;
        op[2 * 32 + lo] = (Oa[2][r] + row[2 * 32 + lo]) * li;
        op[3 * 32 + lo] = (Oa[3][r] + row[3 * 32 + lo]) * li;
      }
    }
  }
}

extern "C" void kernel_launch(void* const* d_in, const int* in_sizes, int n_in,
                              void* d_out, int out_size, void* d_ws, size_t ws_size,
                              hipStream_t stream) {
  const float* q = (const float*)d_in[0];
  const float* k = (const float*)d_in[1];
  const float* v = (const float*)d_in[2];
  const int* cuq = (const int*)d_in[3];
  const int* cuk = (const int*)d_in[4];
  float* out = (float*)d_out;
  const int T = in_sizes[0] / (HH * DD);
  const int B = in_sizes[3] - 1;

  unsigned short* kb2 = (unsigned short*)d_ws;
  unsigned short* vb2 = kb2 + (size_t)T * HH * DD;
  const size_t need = (size_t)T * HH * DD * 2 * 2;
  if (ws_size < need) return;

  {
    zero_rows<<<(T + 255) / 256, 256, 0, stream>>>(cuq, out, T, B);
  }
  {
    const int total = (T >> 5) * HH * 512;
    kvconv<<<(2 * total + 255) / 256, 256, 0, stream>>>(k, v, kb2, vb2, T);
  }
  {
    const int BH = B * HH;
    const int scap = MAXSEQ < T ? MAXSEQ : T;
    const int qtiles = (scap + QBLK - 1) / QBLK;
    attn_main<<<BH * qtiles, 256, 33280, stream>>>(q, kb2, vb2, cuq, cuk, out, T, BH);
  }
}

// Round 15
// 100.009 us; speedup vs baseline: 1.2408x; 1.2408x over previous
//
#include <hip/hip_runtime.h>
#include <hip/hip_bf16.h>
#include <stdint.h>

#define HH 8
#define DD 128
#define MAXSEQ 2048
#define QBLK 128

typedef float f32x16 __attribute__((ext_vector_type(16)));
typedef short s16x8 __attribute__((ext_vector_type(8)));

__device__ __forceinline__ unsigned short f2bf(float x) {
  union { float f; uint32_t u; } v; v.f = x;
  uint32_t u = v.u;
  return (unsigned short)((u + 0x7FFFu + ((u >> 16) & 1u)) >> 16);
}

__device__ __forceinline__ void gload_lds16(const unsigned short* g, unsigned short* l) {
  __builtin_amdgcn_global_load_lds((const __attribute__((address_space(1))) void*)g,
                                   (__attribute__((address_space(3))) void*)l, 16, 0, 0);
}

// ---- fused prepass: K,V [T,H,D] f32 -> fragment-native bf16 unit layouts,
// plus a third grid segment that zeroes output rows not covered by any sequence
// (disjoint from attention-written rows -> order-independent, safe to fuse).
// K unit u = ((h*TBc+tb)*8 + c)*64 + lane: K[tb*32 + (lane&31)][c*16 + (lane>>5)*8 + j]
// V unit u = ((h*TBc+tb)*8 + ks2*4+dt)*64 + lane:
//   V[tb*32 + pi(16ks2 + 8*(lane>>5) + j)][dt*32 + (lane&31)], j=0..7
//   pi: j<4 -> 16ks2 + 4*(lane>>5) + j ; j>=4 -> 16ks2 + 8 + 4*(lane>>5) + (j-4)
// pi makes each lane's QK scores exactly its PV A-fragment (no cross-lane exchange).
__global__ void kvconv(const float* __restrict__ k, const float* __restrict__ v,
                       unsigned short* __restrict__ kb2, unsigned short* __restrict__ vb2,
                       const int* __restrict__ cuq, float* __restrict__ out,
                       int T, int B) {
  const int TBc = T >> 5;
  const int total = TBc * HH * 512;
  int u = blockIdx.x * blockDim.x + threadIdx.x;
  if (u < total) {
    const int lp = u & 63;
    const int key = lp & 31, hi = lp >> 5;
    int r = u >> 6;
    const int c = r & 7; r >>= 3;
    const int tb = r % TBc;
    const int h = r / TBc;
    const int t = tb * 32 + key;
    const int d = c * 16 + hi * 8;
    const float* src = k + ((size_t)t * HH + h) * DD + d;
    float4 a = *(const float4*)src;
    float4 cc = *(const float4*)(src + 4);
    union { unsigned short us[8]; uint4 q; } w;
    w.us[0] = f2bf(a.x); w.us[1] = f2bf(a.y); w.us[2] = f2bf(a.z); w.us[3] = f2bf(a.w);
    w.us[4] = f2bf(cc.x); w.us[5] = f2bf(cc.y); w.us[6] = f2bf(cc.z); w.us[7] = f2bf(cc.w);
    *(uint4*)(kb2 + (size_t)u * 8) = w.q;
  } else if ((u -= total) < total) {
    const int lo = u & 31;
    const int hi = (u >> 5) & 1;
    const int i = (u >> 6) & 7;
    const int dt = i & 3, ks2 = i >> 2;
    int r = u >> 9;
    const int tb = r % TBc;
    const int h = r / TBc;
    const int d = dt * 32 + lo;
    union { unsigned short us[8]; uint4 q; } w;
#pragma unroll
    for (int j = 0; j < 8; ++j) {
      const int phys = 16 * ks2 + ((j < 4) ? (4 * hi + j) : (8 + 4 * hi + (j - 4)));
      const int t = tb * 32 + phys;
      w.us[j] = f2bf(v[((size_t)t * HH + h) * DD + d]);
    }
    *(uint4*)(vb2 + (size_t)u * 8) = w.q;
  } else if ((u -= total) < T) {
    const int t = u;
    bool covered = false;
    for (int b = 0; b < B; ++b) {
      const int s = cuq[b];
      const int len = min(cuq[b + 1] - s, MAXSEQ);
      if (t >= s && t < s + len) covered = true;
    }
    if (!covered) {
      float4* p = (float4*)(out + (size_t)t * HH * DD);
#pragma unroll 4
      for (int i = 0; i < HH * DD / 4; ++i) p[i] = float4{0.f, 0.f, 0.f, 0.f};
    }
  }
}

// ---- main (R10 verbatim — the measured optimum): 4 waves x 32q, KV shared via
// LDS dbuf (64-key tiles), fragment-native LDS layout = linear copy of prepass
// units -> conflict-free contiguous ds_read_b128, linear global_load_lds staging,
// pi-permuted V -> zero-exchange P, fixed-shift softmax, one barrier per tile.
__global__ __launch_bounds__(256, 2)
void attn_main(const float* __restrict__ q,
               const unsigned short* __restrict__ kb2,
               const unsigned short* __restrict__ vb2,
               const int* __restrict__ cuq,
               const int* __restrict__ cuk,
               float* __restrict__ out,
               int T, int BH) {
  extern __shared__ __align__(16) unsigned short smem[];
  // K buf b: smem + b*8192 (2 tile-blocks of 4096); V buf b: smem + 16384 + b*8192

  const int TBc = T >> 5;
  const int bid = blockIdx.x;
  const int bh = bid % BH;
  const int qt = bid / BH;
  const int b = bh / HH, h = bh % HH;
  const int qs = cuq[b], qe = cuq[b + 1];
  const int ks = cuk[b], ke = cuk[b + 1];
  const int nq = min(qe - qs, MAXSEQ);
  const int nk = min(ke - ks, MAXSEQ);
  if (qt * QBLK >= nq || nk <= 0) return;

  const int tid = threadIdx.x;
  const int wave = tid >> 6;
  const int lane = tid & 63;
  const int lo = lane & 31;
  const int hi = lane >> 5;
  const int wub = (tid & ~63) * 8;  // wave-uniform LDS short-offset for staging

  const int kb32 = ks >> 5;  // sequence starts 32-aligned in this problem
  const unsigned short* kb2h = kb2 + (size_t)h * TBc * 4096;
  const unsigned short* vb2h = vb2 + (size_t)h * TBc * 4096;

  // ---- Q fragments; fold 1/sqrt(D)*log2(e) ----
  const float SC = (1.0f / 11.313708498984761f) * 1.4426950408889634f;
  const int qrow = qt * QBLK + wave * 32 + lo;
  const int qg = qs + min(qrow, nq - 1);
  const float* qp = q + ((size_t)qg * HH + h) * DD;
  s16x8 qf[8];
#pragma unroll
  for (int c = 0; c < 8; ++c) {
    const float* p0 = qp + c * 16 + hi * 8;
    float4 a = *(const float4*)(p0);
    float4 cc = *(const float4*)(p0 + 4);
    union { unsigned short us[8]; s16x8 v; } u;
    u.us[0] = f2bf(a.x * SC); u.us[1] = f2bf(a.y * SC);
    u.us[2] = f2bf(a.z * SC); u.us[3] = f2bf(a.w * SC);
    u.us[4] = f2bf(cc.x * SC); u.us[5] = f2bf(cc.y * SC);
    u.us[6] = f2bf(cc.z * SC); u.us[7] = f2bf(cc.w * SC);
    qf[c] = u.v;
  }

  f32x16 Oa[4];
#pragma unroll
  for (int i = 0; i < 4; ++i)
#pragma unroll
    for (int r = 0; r < 16; ++r) Oa[i][r] = 0.0f;

  float l_run = 0.0f;
  const int nkt = (nk + 63) / 64;

  // ---- staging: linear copy of 2 K tile-blocks + 2 V tile-blocks (16KB each) ----
  auto stage = [&](int buf, int kt) {
    unsigned short* Kd = smem + buf * 8192;
    unsigned short* Vd = smem + 16384 + buf * 8192;
#pragma unroll
    for (int r = 0; r < 4; ++r) {
      const int u = r * 256 + tid;
      const int tb = min(kb32 + 2 * kt + (u >> 9), TBc - 1);
      gload_lds16(kb2h + (size_t)tb * 4096 + (size_t)(u & 511) * 8, Kd + (size_t)(r * 256) * 8 + wub);
    }
#pragma unroll
    for (int r = 0; r < 4; ++r) {
      const int u = r * 256 + tid;
      const int tb = min(kb32 + 2 * kt + (u >> 9), TBc - 1);
      gload_lds16(vb2h + (size_t)tb * 4096 + (size_t)(u & 511) * 8, Vd + (size_t)(r * 256) * 8 + wub);
    }
  };

  stage(0, 0);
  __syncthreads();

  int buf = 0;
  for (int kt = 0; kt < nkt; ++kt) {
    if (kt + 1 < nkt) stage(buf ^ 1, kt + 1);

    const unsigned short* Kb = smem + buf * 8192;
    const unsigned short* Vb = smem + 16384 + buf * 8192;

    // ---- QK: two 32-key halves, conflict-free frag reads ----
    f32x16 st0, st1;
#pragma unroll
    for (int r = 0; r < 16; ++r) { st0[r] = 0.0f; st1[r] = 0.0f; }
    {
      s16x8 kfA[8], kfB[8];
#pragma unroll
      for (int c = 0; c < 8; ++c) kfA[c] = *(const s16x8*)(Kb + c * 512 + lane * 8);
#pragma unroll
      for (int c = 0; c < 8; ++c) kfB[c] = *(const s16x8*)(Kb + 4096 + c * 512 + lane * 8);
      __builtin_amdgcn_s_setprio(1);
#pragma unroll
      for (int c = 0; c < 8; ++c) {
        st0 = __builtin_amdgcn_mfma_f32_32x32x16_bf16(kfA[c], qf[c], st0, 0, 0, 0);
        st1 = __builtin_amdgcn_mfma_f32_32x32x16_bf16(kfB[c], qf[c], st1, 0, 0, 0);
      }
      __builtin_amdgcn_s_setprio(0);
    }

    // ---- tail mask (last tile only) ----
    const int lim = nk - kt * 64;
    if (lim < 64) {
#pragma unroll
      for (int r = 0; r < 16; ++r) {
        const int a = (r & 3) + 8 * (r >> 2) + 4 * hi;
        if (a >= lim) st0[r] = -__builtin_inff();
        if (a + 32 >= lim) st1[r] = -__builtin_inff();
      }
    }

    // ---- fixed-shift softmax (no shift; shift-invariance + O/l cancels) ----
    float p[32];
#pragma unroll
    for (int r = 0; r < 16; ++r) {
      p[r] = __builtin_amdgcn_exp2f(st0[r]);
      p[16 + r] = __builtin_amdgcn_exp2f(st1[r]);
    }
    float ps = 0.f;
#pragma unroll
    for (int r = 0; r < 32; r += 4) ps += (p[r] + p[r + 1]) + (p[r + 2] + p[r + 3]);
    l_run += ps;

    // ---- pack: pa(H, ks2) = cvt_pk of p[H*16 + 8*ks2 .. +7] (lane-local, pi-layout) ----
    uint32_t pw[16];
#pragma unroll
    for (int g = 0; g < 8; ++g) {
      uint32_t w0, w1;
      asm("v_cvt_pk_bf16_f32 %0, %1, %2" : "=v"(w0) : "v"(p[4 * g + 0]), "v"(p[4 * g + 1]));
      asm("v_cvt_pk_bf16_f32 %0, %1, %2" : "=v"(w1) : "v"(p[4 * g + 2]), "v"(p[4 * g + 3]));
      pw[2 * g] = w0;
      pw[2 * g + 1] = w1;
    }

    // ---- PV: O += P*V over 2 halves x 2 key-slots x 4 d-tiles ----
    {
      s16x8 vf[16];
#pragma unroll
      for (int i = 0; i < 8; ++i) vf[i] = *(const s16x8*)(Vb + i * 512 + lane * 8);
#pragma unroll
      for (int i = 0; i < 8; ++i) vf[8 + i] = *(const s16x8*)(Vb + 4096 + i * 512 + lane * 8);
      __builtin_amdgcn_s_setprio(1);
#pragma unroll
      for (int Hk = 0; Hk < 4; ++Hk) {  // Hk = H*2 + ks2
        union { uint32_t u[4]; s16x8 v; } pa;
        pa.u[0] = pw[4 * Hk + 0]; pa.u[1] = pw[4 * Hk + 1];
        pa.u[2] = pw[4 * Hk + 2]; pa.u[3] = pw[4 * Hk + 3];
        const int H = Hk >> 1, ks2 = Hk & 1;
#pragma unroll
        for (int dt = 0; dt < 4; ++dt)
          Oa[dt] = __builtin_amdgcn_mfma_f32_32x32x16_bf16(pa.v, vf[H * 8 + ks2 * 4 + dt], Oa[dt], 0, 0, 0);
      }
      __builtin_amdgcn_s_setprio(0);
    }

    if (kt + 1 < nkt) {
      __syncthreads();  // drains this tile's stage loads + joins waves
      buf ^= 1;
    }
  }

  // ---- epilogue: cross-half l reduce, then out[q] = O[q]/l ----
  l_run += __shfl_xor(l_run, 32);
  const float linv = 1.0f / l_run;
#pragma unroll
  for (int r = 0; r < 16; ++r) {
    const int src = (r & 3) + 8 * (r >> 2) + 4 * hi;
    const float li = __shfl(linv, src);
    const int qirow = qt * QBLK + wave * 32 + src;
    if (qirow < nq) {
      float* op = out + ((size_t)(qs + qirow) * HH + h) * DD;
      op[0 * 32 + lo] = Oa[0][r] * li;
      op[1 * 32 + lo] = Oa[1][r] * li;
      op[2 * 32 + lo] = Oa[2][r] * li;
      op[3 * 32 + lo] = Oa[3][r] * li;
    }
  }
}

extern "C" void kernel_launch(void* const* d_in, const int* in_sizes, int n_in,
                              void* d_out, int out_size, void* d_ws, size_t ws_size,
                              hipStream_t stream) {
  const float* q = (const float*)d_in[0];
  const float* k = (const float*)d_in[1];
  const float* v = (const float*)d_in[2];
  const int* cuq = (const int*)d_in[3];
  const int* cuk = (const int*)d_in[4];
  float* out = (float*)d_out;
  const int T = in_sizes[0] / (HH * DD);
  const int B = in_sizes[3] - 1;

  unsigned short* kb2 = (unsigned short*)d_ws;
  unsigned short* vb2 = kb2 + (size_t)T * HH * DD;
  const size_t need = (size_t)T * HH * DD * 2 * 2;
  if (ws_size < need) return;

  {
    const int total = (T >> 5) * HH * 512;
    const long nthreads = 2L * total + T;
    kvconv<<<(int)((nthreads + 255) / 256), 256, 0, stream>>>(k, v, kb2, vb2, cuq, out, T, B);
  }
  {
    const int BH = B * HH;
    const int scap = MAXSEQ < T ? MAXSEQ : T;
    const int qtiles = (scap + QBLK - 1) / QBLK;
    attn_main<<<BH * qtiles, 256, 65536, stream>>>(q, kb2, vb2, cuq, cuk, out, T, BH);
  }
}

// Round 16
// 98.971 us; speedup vs baseline: 1.2538x; 1.0105x over previous
//
#include <hip/hip_runtime.h>
#include <hip/hip_bf16.h>
#include <stdint.h>

#define HH 8
#define DD 128
#define MAXSEQ 2048
#define QBLK 128

typedef float f32x16 __attribute__((ext_vector_type(16)));
typedef short s16x8 __attribute__((ext_vector_type(8)));

__device__ __forceinline__ unsigned short f2bf(float x) {
  union { float f; uint32_t u; } v; v.f = x;
  uint32_t u = v.u;
  return (unsigned short)((u + 0x7FFFu + ((u >> 16) & 1u)) >> 16);
}

__device__ __forceinline__ void gload_lds16(const unsigned short* g, unsigned short* l) {
  __builtin_amdgcn_global_load_lds((const __attribute__((address_space(1))) void*)g,
                                   (__attribute__((address_space(3))) void*)l, 16, 0, 0);
}

// ---- fused prepass: K,V [T,H,D] f32 -> fragment-native bf16 unit layouts,
// plus a third grid segment zeroing output rows not covered by any sequence.
// K unit u = ((h*TBc+tb)*8 + c)*64 + lane: K[tb*32 + (lane&31)][c*16 + (lane>>5)*8 + j]
// V unit u = ((h*TBc+tb)*8 + ks2*4+dt)*64 + lane:
//   V[tb*32 + pi(16ks2 + 8*(lane>>5) + j)][dt*32 + (lane&31)], j=0..7
//   pi: j<4 -> 16ks2 + 4*(lane>>5) + j ; j>=4 -> 16ks2 + 8 + 4*(lane>>5) + (j-4)
__global__ void kvconv(const float* __restrict__ k, const float* __restrict__ v,
                       unsigned short* __restrict__ kb2, unsigned short* __restrict__ vb2,
                       const int* __restrict__ cuq, float* __restrict__ out,
                       int T, int B) {
  const int TBc = T >> 5;
  const int total = TBc * HH * 512;
  int u = blockIdx.x * blockDim.x + threadIdx.x;
  if (u < total) {
    const int lp = u & 63;
    const int key = lp & 31, hi = lp >> 5;
    int r = u >> 6;
    const int c = r & 7; r >>= 3;
    const int tb = r % TBc;
    const int h = r / TBc;
    const int t = tb * 32 + key;
    const int d = c * 16 + hi * 8;
    const float* src = k + ((size_t)t * HH + h) * DD + d;
    float4 a = *(const float4*)src;
    float4 cc = *(const float4*)(src + 4);
    union { unsigned short us[8]; uint4 q; } w;
    w.us[0] = f2bf(a.x); w.us[1] = f2bf(a.y); w.us[2] = f2bf(a.z); w.us[3] = f2bf(a.w);
    w.us[4] = f2bf(cc.x); w.us[5] = f2bf(cc.y); w.us[6] = f2bf(cc.z); w.us[7] = f2bf(cc.w);
    *(uint4*)(kb2 + (size_t)u * 8) = w.q;
  } else if ((u -= total) < total) {
    const int lo = u & 31;
    const int hi = (u >> 5) & 1;
    const int i = (u >> 6) & 7;
    const int dt = i & 3, ks2 = i >> 2;
    int r = u >> 9;
    const int tb = r % TBc;
    const int h = r / TBc;
    const int d = dt * 32 + lo;
    union { unsigned short us[8]; uint4 q; } w;
#pragma unroll
    for (int j = 0; j < 8; ++j) {
      const int phys = 16 * ks2 + ((j < 4) ? (4 * hi + j) : (8 + 4 * hi + (j - 4)));
      const int t = tb * 32 + phys;
      w.us[j] = f2bf(v[((size_t)t * HH + h) * DD + d]);
    }
    *(uint4*)(vb2 + (size_t)u * 8) = w.q;
  } else if ((u -= total) < T) {
    const int t = u;
    bool covered = false;
    for (int b = 0; b < B; ++b) {
      const int s = cuq[b];
      const int len = min(cuq[b + 1] - s, MAXSEQ);
      if (t >= s && t < s + len) covered = true;
    }
    if (!covered) {
      float4* p = (float4*)(out + (size_t)t * HH * DD);
#pragma unroll 4
      for (int i = 0; i < HH * DD / 4; ++i) p[i] = float4{0.f, 0.f, 0.f, 0.f};
    }
  }
}

// ---- main (R10 structure + issue-shadow reorder + persistent-zero C):
// 4 waves x 32q, KV shared via LDS dbuf (64-key tiles), fragment-native linear
// layout (conflict-free ds_read_b128), linear global_load_lds staging,
// pi-permuted V -> zero-exchange P, fixed-shift softmax, one barrier per tile.
// Per tile: QK0+QK1 -> sm0/pack0 -> PV0 issue -> sm1/pack1 (in PV0's MFMA
// shadow) -> PV1. First MFMA of each chain takes a persistent zero C (no
// per-iter accumulator re-zeroing movs).
__global__ __launch_bounds__(256, 2)
void attn_main(const float* __restrict__ q,
               const unsigned short* __restrict__ kb2,
               const unsigned short* __restrict__ vb2,
               const int* __restrict__ cuq,
               const int* __restrict__ cuk,
               float* __restrict__ out,
               int T, int BH) {
  extern __shared__ __align__(16) unsigned short smem[];
  // K buf b: smem + b*8192 (2 tile-blocks of 4096); V buf b: smem + 16384 + b*8192

  const int TBc = T >> 5;
  const int bid = blockIdx.x;
  const int bh = bid % BH;
  const int qt = bid / BH;
  const int b = bh / HH, h = bh % HH;
  const int qs = cuq[b], qe = cuq[b + 1];
  const int ks = cuk[b], ke = cuk[b + 1];
  const int nq = min(qe - qs, MAXSEQ);
  const int nk = min(ke - ks, MAXSEQ);
  if (qt * QBLK >= nq || nk <= 0) return;

  const int tid = threadIdx.x;
  const int wave = tid >> 6;
  const int lane = tid & 63;
  const int lo = lane & 31;
  const int hi = lane >> 5;
  const int wub = (tid & ~63) * 8;  // wave-uniform LDS short-offset for staging

  const int kb32 = ks >> 5;  // sequence starts 32-aligned in this problem
  const unsigned short* kb2h = kb2 + (size_t)h * TBc * 4096;
  const unsigned short* vb2h = vb2 + (size_t)h * TBc * 4096;

  // ---- Q fragments; fold 1/sqrt(D)*log2(e) ----
  const float SC = (1.0f / 11.313708498984761f) * 1.4426950408889634f;
  const int qrow = qt * QBLK + wave * 32 + lo;
  const int qg = qs + min(qrow, nq - 1);
  const float* qp = q + ((size_t)qg * HH + h) * DD;
  s16x8 qf[8];
#pragma unroll
  for (int c = 0; c < 8; ++c) {
    const float* p0 = qp + c * 16 + hi * 8;
    float4 a = *(const float4*)(p0);
    float4 cc = *(const float4*)(p0 + 4);
    union { unsigned short us[8]; s16x8 v; } u;
    u.us[0] = f2bf(a.x * SC); u.us[1] = f2bf(a.y * SC);
    u.us[2] = f2bf(a.z * SC); u.us[3] = f2bf(a.w * SC);
    u.us[4] = f2bf(cc.x * SC); u.us[5] = f2bf(cc.y * SC);
    u.us[6] = f2bf(cc.z * SC); u.us[7] = f2bf(cc.w * SC);
    qf[c] = u.v;
  }

  f32x16 Oa[4];
#pragma unroll
  for (int i = 0; i < 4; ++i)
#pragma unroll
    for (int r = 0; r < 16; ++r) Oa[i][r] = 0.0f;

  // persistent zero C-operand (init once; first MFMA of each QK chain reads it)
  f32x16 zv;
#pragma unroll
  for (int r = 0; r < 16; ++r) zv[r] = 0.0f;

  float l_run = 0.0f;
  const int nkt = (nk + 63) / 64;

  // ---- staging: linear copy of 2 K tile-blocks + 2 V tile-blocks (16KB each) ----
  auto stage = [&](int buf, int kt) {
    unsigned short* Kd = smem + buf * 8192;
    unsigned short* Vd = smem + 16384 + buf * 8192;
#pragma unroll
    for (int r = 0; r < 4; ++r) {
      const int u = r * 256 + tid;
      const int tb = min(kb32 + 2 * kt + (u >> 9), TBc - 1);
      gload_lds16(kb2h + (size_t)tb * 4096 + (size_t)(u & 511) * 8, Kd + (size_t)(r * 256) * 8 + wub);
    }
#pragma unroll
    for (int r = 0; r < 4; ++r) {
      const int u = r * 256 + tid;
      const int tb = min(kb32 + 2 * kt + (u >> 9), TBc - 1);
      gload_lds16(vb2h + (size_t)tb * 4096 + (size_t)(u & 511) * 8, Vd + (size_t)(r * 256) * 8 + wub);
    }
  };

  stage(0, 0);
  __syncthreads();

  int buf = 0;
  for (int kt = 0; kt < nkt; ++kt) {
    if (kt + 1 < nkt) stage(buf ^ 1, kt + 1);

    const unsigned short* Kb = smem + buf * 8192;
    const unsigned short* Vb = smem + 16384 + buf * 8192;

    // ---- QK: two 32-key halves, conflict-free frag reads; C of first MFMA = zv ----
    f32x16 st0, st1;
    {
      s16x8 kfA[8], kfB[8];
#pragma unroll
      for (int c = 0; c < 8; ++c) kfA[c] = *(const s16x8*)(Kb + c * 512 + lane * 8);
#pragma unroll
      for (int c = 0; c < 8; ++c) kfB[c] = *(const s16x8*)(Kb + 4096 + c * 512 + lane * 8);
      __builtin_amdgcn_s_setprio(1);
      st0 = __builtin_amdgcn_mfma_f32_32x32x16_bf16(kfA[0], qf[0], zv, 0, 0, 0);
      st1 = __builtin_amdgcn_mfma_f32_32x32x16_bf16(kfB[0], qf[0], zv, 0, 0, 0);
#pragma unroll
      for (int c = 1; c < 8; ++c) {
        st0 = __builtin_amdgcn_mfma_f32_32x32x16_bf16(kfA[c], qf[c], st0, 0, 0, 0);
        st1 = __builtin_amdgcn_mfma_f32_32x32x16_bf16(kfB[c], qf[c], st1, 0, 0, 0);
      }
      __builtin_amdgcn_s_setprio(0);
    }

    // ---- V frag reads issued up front (lgkm queue fills under softmax) ----
    s16x8 vf[16];
#pragma unroll
    for (int i = 0; i < 8; ++i) vf[i] = *(const s16x8*)(Vb + i * 512 + lane * 8);
#pragma unroll
    for (int i = 0; i < 8; ++i) vf[8 + i] = *(const s16x8*)(Vb + 4096 + i * 512 + lane * 8);

    // ---- tail mask (last tile only) ----
    const int lim = nk - kt * 64;
    if (lim < 64) {
#pragma unroll
      for (int r = 0; r < 16; ++r) {
        const int a = (r & 3) + 8 * (r >> 2) + 4 * hi;
        if (a >= lim) st0[r] = -__builtin_inff();
        if (a + 32 >= lim) st1[r] = -__builtin_inff();
      }
    }

    // ---- half 0: softmax + pack (runs in QK1-pipe shadow) ----
    float p0[16];
#pragma unroll
    for (int r = 0; r < 16; ++r) p0[r] = __builtin_amdgcn_exp2f(st0[r]);
    float ps0 = 0.f;
#pragma unroll
    for (int r = 0; r < 16; r += 4) ps0 += (p0[r] + p0[r + 1]) + (p0[r + 2] + p0[r + 3]);
    uint32_t pw0[8];
#pragma unroll
    for (int g = 0; g < 4; ++g) {
      uint32_t w0, w1;
      asm("v_cvt_pk_bf16_f32 %0, %1, %2" : "=v"(w0) : "v"(p0[4 * g + 0]), "v"(p0[4 * g + 1]));
      asm("v_cvt_pk_bf16_f32 %0, %1, %2" : "=v"(w1) : "v"(p0[4 * g + 2]), "v"(p0[4 * g + 3]));
      pw0[2 * g] = w0;
      pw0[2 * g + 1] = w1;
    }

    // ---- PV half 0 issue (8 MFMA; its pipe time shadows softmax of half 1) ----
    __builtin_amdgcn_s_setprio(1);
#pragma unroll
    for (int ks2 = 0; ks2 < 2; ++ks2) {
      union { uint32_t u[4]; s16x8 v; } pa;
      pa.u[0] = pw0[4 * ks2 + 0]; pa.u[1] = pw0[4 * ks2 + 1];
      pa.u[2] = pw0[4 * ks2 + 2]; pa.u[3] = pw0[4 * ks2 + 3];
#pragma unroll
      for (int dt = 0; dt < 4; ++dt)
        Oa[dt] = __builtin_amdgcn_mfma_f32_32x32x16_bf16(pa.v, vf[ks2 * 4 + dt], Oa[dt], 0, 0, 0);
    }
    __builtin_amdgcn_s_setprio(0);

    // ---- half 1: softmax + pack (VALU in PV0's MFMA shadow) ----
    float p1[16];
#pragma unroll
    for (int r = 0; r < 16; ++r) p1[r] = __builtin_amdgcn_exp2f(st1[r]);
    float ps1 = 0.f;
#pragma unroll
    for (int r = 0; r < 16; r += 4) ps1 += (p1[r] + p1[r + 1]) + (p1[r + 2] + p1[r + 3]);
    l_run += ps0 + ps1;
    uint32_t pw1[8];
#pragma unroll
    for (int g = 0; g < 4; ++g) {
      uint32_t w0, w1;
      asm("v_cvt_pk_bf16_f32 %0, %1, %2" : "=v"(w0) : "v"(p1[4 * g + 0]), "v"(p1[4 * g + 1]));
      asm("v_cvt_pk_bf16_f32 %0, %1, %2" : "=v"(w1) : "v"(p1[4 * g + 2]), "v"(p1[4 * g + 3]));
      pw1[2 * g] = w0;
      pw1[2 * g + 1] = w1;
    }

    // ---- PV half 1 ----
    __builtin_amdgcn_s_setprio(1);
#pragma unroll
    for (int ks2 = 0; ks2 < 2; ++ks2) {
      union { uint32_t u[4]; s16x8 v; } pa;
      pa.u[0] = pw1[4 * ks2 + 0]; pa.u[1] = pw1[4 * ks2 + 1];
      pa.u[2] = pw1[4 * ks2 + 2]; pa.u[3] = pw1[4 * ks2 + 3];
#pragma unroll
      for (int dt = 0; dt < 4; ++dt)
        Oa[dt] = __builtin_amdgcn_mfma_f32_32x32x16_bf16(pa.v, vf[8 + ks2 * 4 + dt], Oa[dt], 0, 0, 0);
    }
    __builtin_amdgcn_s_setprio(0);

    if (kt + 1 < nkt) {
      __syncthreads();  // drains this tile's stage loads + joins waves
      buf ^= 1;
    }
  }

  // ---- epilogue: cross-half l reduce, then out[q] = O[q]/l ----
  l_run += __shfl_xor(l_run, 32);
  const float linv = 1.0f / l_run;
#pragma unroll
  for (int r = 0; r < 16; ++r) {
    const int src = (r & 3) + 8 * (r >> 2) + 4 * hi;
    const float li = __shfl(linv, src);
    const int qirow = qt * QBLK + wave * 32 + src;
    if (qirow < nq) {
      float* op = out + ((size_t)(qs + qirow) * HH + h) * DD;
      op[0 * 32 + lo] = Oa[0][r] * li;
      op[1 * 32 + lo] = Oa[1][r] * li;
      op[2 * 32 + lo] = Oa[2][r] * li;
      op[3 * 32 + lo] = Oa[3][r] * li;
    }
  }
}

extern "C" void kernel_launch(void* const* d_in, const int* in_sizes, int n_in,
                              void* d_out, int out_size, void* d_ws, size_t ws_size,
                              hipStream_t stream) {
  const float* q = (const float*)d_in[0];
  const float* k = (const float*)d_in[1];
  const float* v = (const float*)d_in[2];
  const int* cuq = (const int*)d_in[3];
  const int* cuk = (const int*)d_in[4];
  float* out = (float*)d_out;
  const int T = in_sizes[0] / (HH * DD);
  const int B = in_sizes[3] - 1;

  unsigned short* kb2 = (unsigned short*)d_ws;
  unsigned short* vb2 = kb2 + (size_t)T * HH * DD;
  const size_t need = (size_t)T * HH * DD * 2 * 2;
  if (ws_size < need) return;

  {
    const int total = (T >> 5) * HH * 512;
    const long nthreads = 2L * total + T;
    kvconv<<<(int)((nthreads + 255) / 256), 256, 0, stream>>>(k, v, kb2, vb2, cuq, out, T, B);
  }
  {
    const int BH = B * HH;
    const int scap = MAXSEQ < T ? MAXSEQ : T;
    const int qtiles = (scap + QBLK - 1) / QBLK;
    attn_main<<<BH * qtiles, 256, 65536, stream>>>(q, kb2, vb2, cuq, cuk, out, T, BH);
  }
}